// Round 4
// baseline (1822.448 us; speedup 1.0000x reference)
//
#include <hip/hip_runtime.h>
#include <stdint.h>

// Persistent-kernel RNN, R4: two interleaved batch streams (A=rows 0..255,
// B=rows 256..511) hide the inter-wg sync latency behind the other stream's
// compute. W_hh bf16 resident in registers (fB, 128 VGPR/wave). MFMA A-frags
// loaded DIRECTLY global->register (no LDS staging). Vectorized 16-flag poll.

#define BATCH 512
#define SEQ   256
#define HID   1024
#define CLS   128

#define GB 16          // batch groups (per stream)
#define GJ 16          // hidden slices
#define BT 16          // batch rows per wg per stream
#define JT 64          // hidden cols per wg
#define WSTR 1028      // W init-stage row stride (halves)
#define HSTR 72        // h-store exchange row stride (halves), 144 B
#define HDSTR 1032     // head-stage row stride (halves)
#define SMEM_BYTES (JT * WSTR * 2)      // 131584 B (init W stage dominates)
// loop-time LDS overlays (W region dead after fB preload):
#define RBA_OFF 0
#define RBB_OFF 4096
#define HSA_OFF 8192
#define HSB_OFF 12288
#define HEAD_OFF 16384
#define HBUF_HALVES (BATCH * HID)       // 1 MB per buffer

typedef __attribute__((ext_vector_type(8))) short  bf16x8;
typedef __attribute__((ext_vector_type(4))) short  s16x4;
typedef __attribute__((ext_vector_type(4))) float  f32x4;
typedef __attribute__((ext_vector_type(4))) int    i32x4;

__device__ __forceinline__ unsigned short f2bf(float f) {
  unsigned int u = __float_as_uint(f);
  u = (u + 0x7FFFu + ((u >> 16) & 1u)) >> 16;   // RNE
  return (unsigned short)u;
}
__device__ __forceinline__ float b2f(short h) {
  return __uint_as_float(((unsigned int)(unsigned short)h) << 16);
}

// ---- device-coherent (IC) accesses ----
__device__ __forceinline__ void store_flag(int* p, int v) {
  asm volatile("global_store_dword %0, %1, off sc0 sc1" :: "v"(p), "v"(v) : "memory");
}
__device__ __forceinline__ void store16(void* p, i32x4 v) {
  asm volatile("global_store_dwordx4 %0, %1, off sc0 sc1" :: "v"(p), "v"(v) : "memory");
}
__device__ __forceinline__ void waitcnt0() {
  asm volatile("s_waitcnt vmcnt(0)" ::: "memory");
}
__device__ __forceinline__ void barrier_lgkm() {
  asm volatile("s_waitcnt lgkmcnt(0)\n\ts_barrier" ::: "memory");
}
// 4x dwordx4, 64B stride (A-frag blocks: 4 consecutive k-steps)
__device__ __forceinline__ void issue4s(const void* p, i32x4& a, i32x4& b, i32x4& c, i32x4& d) {
  asm volatile(
    "global_load_dwordx4 %0, %4, off sc0 sc1\n\t"
    "global_load_dwordx4 %1, %4, off offset:64 sc0 sc1\n\t"
    "global_load_dwordx4 %2, %4, off offset:128 sc0 sc1\n\t"
    "global_load_dwordx4 %3, %4, off offset:192 sc0 sc1"
    : "=&v"(a), "=&v"(b), "=&v"(c), "=&v"(d)
    : "v"(p) : "memory");
}
// 4x dwordx4, contiguous 64B (head staging)
__device__ __forceinline__ void issue4c(const void* p, i32x4& a, i32x4& b, i32x4& c, i32x4& d) {
  asm volatile(
    "global_load_dwordx4 %0, %4, off sc0 sc1\n\t"
    "global_load_dwordx4 %1, %4, off offset:16 sc0 sc1\n\t"
    "global_load_dwordx4 %2, %4, off offset:32 sc0 sc1\n\t"
    "global_load_dwordx4 %3, %4, off offset:48 sc0 sc1"
    : "=&v"(a), "=&v"(b), "=&v"(c), "=&v"(d)
    : "v"(p) : "memory");
}
#define DEF_WAIT(NAME, N) \
__device__ __forceinline__ void NAME(i32x4& a, i32x4& b, i32x4& c, i32x4& d) { \
  asm volatile("s_waitcnt vmcnt(" #N ")" : "+v"(a), "+v"(b), "+v"(c), "+v"(d) :: "memory"); \
}
DEF_WAIT(wait_vm12, 12)
DEF_WAIT(wait_vm8, 8)
DEF_WAIT(wait_vm4, 4)
DEF_WAIT(wait_vm0, 0)

// one round trip: min of the 16 peer flags (4x dwordx4 of one 64B line)
__device__ __forceinline__ int flags_min16(const int* p) {
  i32x4 f0, f1, f2, f3;
  asm volatile(
    "global_load_dwordx4 %0, %4, off sc0 sc1\n\t"
    "global_load_dwordx4 %1, %4, off offset:16 sc0 sc1\n\t"
    "global_load_dwordx4 %2, %4, off offset:32 sc0 sc1\n\t"
    "global_load_dwordx4 %3, %4, off offset:48 sc0 sc1\n\t"
    "s_waitcnt vmcnt(0)"
    : "=&v"(f0), "=&v"(f1), "=&v"(f2), "=&v"(f3) : "v"(p) : "memory");
  int m = f0.x;
  m = f0.y < m ? f0.y : m;  m = f0.z < m ? f0.z : m;  m = f0.w < m ? f0.w : m;
  m = f1.x < m ? f1.x : m;  m = f1.y < m ? f1.y : m;  m = f1.z < m ? f1.z : m;  m = f1.w < m ? f1.w : m;
  m = f2.x < m ? f2.x : m;  m = f2.y < m ? f2.y : m;  m = f2.z < m ? f2.z : m;  m = f2.w < m ? f2.w : m;
  m = f3.x < m ? f3.x : m;  m = f3.y < m ? f3.y : m;  m = f3.z < m ? f3.z : m;  m = f3.w < m ? f3.w : m;
  return m;
}
// per-wave spin (lane 0 polls; scalar waitcnt also drains this wave's stores)
__device__ __forceinline__ void wave_spin(const int* p, int t, int lane) {
  if (lane == 0) {
    while (flags_min16(p) < t) {}
  }
}

__device__ __forceinline__ float tanh_fast(float z) {
  float e = __expf(2.f * z);
  return 1.f - 2.f / (e + 1.f);
}

__device__ __forceinline__ void mfma2(i32x4 av, bf16x8 fb0, bf16x8 fb1,
                                      f32x4& acc0, f32x4& acc1) {
  union { i32x4 i; bf16x8 v8; } u; u.i = av;
  acc0 = __builtin_amdgcn_mfma_f32_16x16x32_bf16(u.v8, fb0, acc0, 0, 0, 0);
  acc1 = __builtin_amdgcn_mfma_f32_16x16x32_bf16(u.v8, fb1, acc1, 0, 0, 0);
}

__global__ void __launch_bounds__(256, 1)
rnn_persistent(const float* __restrict__ x, const float* __restrict__ Whx,
               const float* __restrict__ Whh, const float* __restrict__ bh,
               const float* __restrict__ Wph, const float* __restrict__ bp,
               float* __restrict__ out, unsigned short* hbuf,
               int* flagsA, int* flagsB)
{
  extern __shared__ short smem[];
  short* sW   = smem;                                // init-only
  float* rbA  = (float*)((char*)smem + RBA_OFF);
  float* rbB  = (float*)((char*)smem + RBB_OFF);
  short* hSA  = (short*)((char*)smem + HSA_OFF);
  short* hSB  = (short*)((char*)smem + HSB_OFF);
  short* hd   = (short*)((char*)smem + HEAD_OFF);

  const int tid  = threadIdx.x;
  const int bg   = blockIdx.x & 15;
  const int jg   = blockIdx.x >> 4;
  const int lane = tid & 63;
  const int wv   = tid >> 6;
  const int l15  = lane & 15;
  const int quad = lane >> 4;
  const int npair = wv & 1;    // n-block: cols [npair*32, +32)
  const int khalf = wv >> 1;   // k-half:  k in [khalf*512, +512)

  // ---- stage W_hh slice into LDS as bf16 (init only) ----
  {
    const int jr = tid >> 2;
    const int kq = tid & 3;
    const float* src = Whh + (jg * JT + jr) * HID + kq * 256;
    short* dst = sW + jr * WSTR + kq * 256;
#pragma unroll 4
    for (int i = 0; i < 64; ++i) {
      float4 f = *(const float4*)(src + i * 4);
      s16x4 h4;
      h4.x = (short)f2bf(f.x); h4.y = (short)f2bf(f.y);
      h4.z = (short)f2bf(f.z); h4.w = (short)f2bf(f.w);
      *(s16x4*)(dst + i * 4) = h4;
    }
  }
  __syncthreads();

  // ---- preload B-fragments: n = npair*32 + nt*16 + l15, k = khalf*512 + kk*32 + quad*8
  bf16x8 fB[2][16];
#pragma unroll
  for (int nt = 0; nt < 2; ++nt) {
    const short* bp_ = sW + (npair * 32 + nt * 16 + l15) * WSTR + khalf * 512 + quad * 8;
#pragma unroll
    for (int kk = 0; kk < 16; ++kk) {
      union { bf16x8 v8; s16x4 h[2]; } u;
      u.h[0] = *(const s16x4*)(bp_ + kk * 32);
      u.h[1] = *(const s16x4*)(bp_ + kk * 32 + 4);
      fB[nt][kk] = u.v8;
    }
  }
  __syncthreads();   // sW dead; overlays live from here

  const int jb0 = jg * JT + npair * 32;
  const float whx0 = Whx[jb0 + l15];
  const float whx1 = Whx[jb0 + 16 + l15];
  const float bh0  = bh[jb0 + l15];
  const float bh1  = bh[jb0 + 16 + l15];

  const int browA = bg * BT;          // stream A rows
  const int browB = 256 + bg * BT;    // stream B rows

  int* mfA = flagsA + bg * 16;        // 16 flags = one 64B line
  int* mfB = flagsB + bg * 16;

  for (int t = 0; t < SEQ; ++t) {
    const unsigned short* hin = hbuf + ((t + 1) & 1) * HBUF_HALVES;
    unsigned short*      hout = hbuf + (t & 1) * HBUF_HALVES;

    // ================= stream A =================
    // (flagsA(t) confirmed by the spin at the bottom of iteration t-1)
    float xv[4];
    if (khalf == 0) {
      const float* xp = x + (browA + quad * 4) * SEQ + t;
#pragma unroll
      for (int r = 0; r < 4; ++r) xv[r] = xp[r * SEQ];
    }
    f32x4 acc0 = {0.f, 0.f, 0.f, 0.f};
    f32x4 acc1 = {0.f, 0.f, 0.f, 0.f};

    if (t > 0) {
      const char* ab = (const char*)(hin + (browA + l15) * HID + khalf * 512 + quad * 8);
      i32x4 a0,a1,a2,a3, b0,b1,b2,b3, c0,c1,c2,c3, d0,d1,d2,d3;
      issue4s(ab,       a0,a1,a2,a3);
      issue4s(ab + 256, b0,b1,b2,b3);
      issue4s(ab + 512, c0,c1,c2,c3);
      issue4s(ab + 768, d0,d1,d2,d3);
      wait_vm12(a0,a1,a2,a3);
      mfma2(a0, fB[0][0],  fB[1][0],  acc0, acc1);
      mfma2(a1, fB[0][1],  fB[1][1],  acc0, acc1);
      mfma2(a2, fB[0][2],  fB[1][2],  acc0, acc1);
      mfma2(a3, fB[0][3],  fB[1][3],  acc0, acc1);
      wait_vm8(b0,b1,b2,b3);
      mfma2(b0, fB[0][4],  fB[1][4],  acc0, acc1);
      mfma2(b1, fB[0][5],  fB[1][5],  acc0, acc1);
      mfma2(b2, fB[0][6],  fB[1][6],  acc0, acc1);
      mfma2(b3, fB[0][7],  fB[1][7],  acc0, acc1);
      wait_vm4(c0,c1,c2,c3);
      mfma2(c0, fB[0][8],  fB[1][8],  acc0, acc1);
      mfma2(c1, fB[0][9],  fB[1][9],  acc0, acc1);
      mfma2(c2, fB[0][10], fB[1][10], acc0, acc1);
      mfma2(c3, fB[0][11], fB[1][11], acc0, acc1);
      wait_vm0(d0,d1,d2,d3);
      mfma2(d0, fB[0][12], fB[1][12], acc0, acc1);
      mfma2(d1, fB[0][13], fB[1][13], acc0, acc1);
      mfma2(d2, fB[0][14], fB[1][14], acc0, acc1);
      mfma2(d3, fB[0][15], fB[1][15], acc0, acc1);
    }
    // k-reduce + epilogue A
    if (khalf == 1) {
      *(f32x4*)(rbA + ((npair * 2 + 0) * 64 + lane) * 4) = acc0;
      *(f32x4*)(rbA + ((npair * 2 + 1) * 64 + lane) * 4) = acc1;
    }
    barrier_lgkm();
    if (khalf == 0) {
      f32x4 p0 = *(const f32x4*)(rbA + ((npair * 2 + 0) * 64 + lane) * 4);
      f32x4 p1 = *(const f32x4*)(rbA + ((npair * 2 + 1) * 64 + lane) * 4);
      acc0 += p0; acc1 += p1;
#pragma unroll
      for (int r = 0; r < 4; ++r) {
        const int row = quad * 4 + r;
        hSA[row * HSTR + npair * 32 + l15]      = (short)f2bf(tanh_fast(acc0[r] + xv[r] * whx0 + bh0));
        hSA[row * HSTR + npair * 32 + 16 + l15] = (short)f2bf(tanh_fast(acc1[r] + xv[r] * whx1 + bh1));
      }
    }
    barrier_lgkm();
    if (tid < 128) {
      union { bf16x8 v8; i32x4 i; } u;
      u.v8 = *(const bf16x8*)(hSA + (tid >> 3) * HSTR + (tid & 7) * 8);
      store16(hout + (browA + (tid >> 3)) * HID + jg * JT + (tid & 7) * 8, u.i);
    }
    // mid sync: spinB drains this wave's A-stores; barrier; post flagA(t+1)
    if (t > 0) wave_spin(mfB, t, lane);
    else       waitcnt0();
    barrier_lgkm();
    if (tid == 0) store_flag(mfA + jg, t + 1);

    // ================= stream B =================
    if (khalf == 0) {
      const float* xp = x + (browB + quad * 4) * SEQ + t;
#pragma unroll
      for (int r = 0; r < 4; ++r) xv[r] = xp[r * SEQ];
    }
    acc0 = (f32x4){0.f, 0.f, 0.f, 0.f};
    acc1 = (f32x4){0.f, 0.f, 0.f, 0.f};

    if (t > 0) {
      const char* ab = (const char*)(hin + (browB + l15) * HID + khalf * 512 + quad * 8);
      i32x4 a0,a1,a2,a3, b0,b1,b2,b3, c0,c1,c2,c3, d0,d1,d2,d3;
      issue4s(ab,       a0,a1,a2,a3);
      issue4s(ab + 256, b0,b1,b2,b3);
      issue4s(ab + 512, c0,c1,c2,c3);
      issue4s(ab + 768, d0,d1,d2,d3);
      wait_vm12(a0,a1,a2,a3);
      mfma2(a0, fB[0][0],  fB[1][0],  acc0, acc1);
      mfma2(a1, fB[0][1],  fB[1][1],  acc0, acc1);
      mfma2(a2, fB[0][2],  fB[1][2],  acc0, acc1);
      mfma2(a3, fB[0][3],  fB[1][3],  acc0, acc1);
      wait_vm8(b0,b1,b2,b3);
      mfma2(b0, fB[0][4],  fB[1][4],  acc0, acc1);
      mfma2(b1, fB[0][5],  fB[1][5],  acc0, acc1);
      mfma2(b2, fB[0][6],  fB[1][6],  acc0, acc1);
      mfma2(b3, fB[0][7],  fB[1][7],  acc0, acc1);
      wait_vm4(c0,c1,c2,c3);
      mfma2(c0, fB[0][8],  fB[1][8],  acc0, acc1);
      mfma2(c1, fB[0][9],  fB[1][9],  acc0, acc1);
      mfma2(c2, fB[0][10], fB[1][10], acc0, acc1);
      mfma2(c3, fB[0][11], fB[1][11], acc0, acc1);
      wait_vm0(d0,d1,d2,d3);
      mfma2(d0, fB[0][12], fB[1][12], acc0, acc1);
      mfma2(d1, fB[0][13], fB[1][13], acc0, acc1);
      mfma2(d2, fB[0][14], fB[1][14], acc0, acc1);
      mfma2(d3, fB[0][15], fB[1][15], acc0, acc1);
    }
    if (khalf == 1) {
      *(f32x4*)(rbB + ((npair * 2 + 0) * 64 + lane) * 4) = acc0;
      *(f32x4*)(rbB + ((npair * 2 + 1) * 64 + lane) * 4) = acc1;
    }
    barrier_lgkm();
    if (khalf == 0) {
      f32x4 p0 = *(const f32x4*)(rbB + ((npair * 2 + 0) * 64 + lane) * 4);
      f32x4 p1 = *(const f32x4*)(rbB + ((npair * 2 + 1) * 64 + lane) * 4);
      acc0 += p0; acc1 += p1;
#pragma unroll
      for (int r = 0; r < 4; ++r) {
        const int row = quad * 4 + r;
        hSB[row * HSTR + npair * 32 + l15]      = (short)f2bf(tanh_fast(acc0[r] + xv[r] * whx0 + bh0));
        hSB[row * HSTR + npair * 32 + 16 + l15] = (short)f2bf(tanh_fast(acc1[r] + xv[r] * whx1 + bh1));
      }
    }
    barrier_lgkm();
    if (tid < 128) {
      union { bf16x8 v8; i32x4 i; } u;
      u.v8 = *(const bf16x8*)(hSB + (tid >> 3) * HSTR + (tid & 7) * 8);
      store16(hout + (browB + (tid >> 3)) * HID + jg * JT + (tid & 7) * 8, u.i);
    }
    // bottom sync: spinA(t+1) drains B-stores; barrier; post flagB(t+1)
    wave_spin(mfA, t + 1, lane);
    barrier_lgkm();
    if (tid == 0) store_flag(mfB + jg, t + 1);
  }

  // ---- output head ----
  wave_spin(mfB, SEQ, lane);   // flagsA==SEQ already confirmed at last bottom
  barrier_lgkm();

  const unsigned short* hlast = hbuf + ((SEQ - 1) & 1) * HBUF_HALVES;
  {
    // stage 32 h rows (A block then B block) into LDS
    const int ri  = tid >> 3;              // 0..31
    const int seg = tid & 7;               // 0..7, 256B each
    const int grow = (ri < 16) ? (browA + ri) : (browB + ri - 16);
    const char* pb = (const char*)(hlast + grow * HID + seg * 128);
    i32x4 p0,p1,p2,p3, q0,q1,q2,q3, r0,r1,r2,r3, s0,s1,s2,s3;
    issue4c(pb,       p0,p1,p2,p3);
    issue4c(pb + 64,  q0,q1,q2,q3);
    issue4c(pb + 128, r0,r1,r2,r3);
    issue4c(pb + 192, s0,s1,s2,s3);
    waitcnt0();
    short* d = hd + ri * HDSTR + seg * 128;
    union { i32x4 i; bf16x8 v8; } u;
    u.i = p0; *(bf16x8*)(d)      = u.v8;  u.i = p1; *(bf16x8*)(d + 8)  = u.v8;
    u.i = p2; *(bf16x8*)(d + 16) = u.v8;  u.i = p3; *(bf16x8*)(d + 24) = u.v8;
    u.i = q0; *(bf16x8*)(d + 32) = u.v8;  u.i = q1; *(bf16x8*)(d + 40) = u.v8;
    u.i = q2; *(bf16x8*)(d + 48) = u.v8;  u.i = q3; *(bf16x8*)(d + 56) = u.v8;
    u.i = r0; *(bf16x8*)(d + 64) = u.v8;  u.i = r1; *(bf16x8*)(d + 72) = u.v8;
    u.i = r2; *(bf16x8*)(d + 80) = u.v8;  u.i = r3; *(bf16x8*)(d + 88) = u.v8;
    u.i = s0; *(bf16x8*)(d + 96) = u.v8;  u.i = s1; *(bf16x8*)(d + 104) = u.v8;
    u.i = s2; *(bf16x8*)(d + 112) = u.v8; u.i = s3; *(bf16x8*)(d + 120) = u.v8;
  }
  __syncthreads();
  {
    const int ri = tid >> 3;               // 0..31 row
    const int cc = tid & 7;
    const int cg = jg * 8 + cc;
    const int grow = (ri < 16) ? (browA + ri) : (browB + ri - 16);
    const float* wp = Wph + cg * HID;
    const short* hs = hd + ri * HDSTR;
    float acc = 0.f;
#pragma unroll 8
    for (int k4 = 0; k4 < 256; ++k4) {
      float4 w = *(const float4*)(wp + k4 * 4);
      s16x4 hv = *(const s16x4*)(hs + k4 * 4);
      acc += b2f(hv.x) * w.x + b2f(hv.y) * w.y + b2f(hv.z) * w.z + b2f(hv.w) * w.w;
    }
    out[grow * CLS + cg] = acc + bp[cg];
  }
}

extern "C" void kernel_launch(void* const* d_in, const int* in_sizes, int n_in,
                              void* d_out, int out_size, void* d_ws, size_t ws_size,
                              hipStream_t stream) {
  const float* x   = (const float*)d_in[0];
  const float* Whx = (const float*)d_in[1];
  const float* Whh = (const float*)d_in[2];
  const float* bh  = (const float*)d_in[3];
  const float* Wph = (const float*)d_in[4];
  const float* bp  = (const float*)d_in[5];
  float* out = (float*)d_out;

  unsigned short* hbuf = (unsigned short*)d_ws;
  int* flagsA = (int*)((char*)d_ws + (size_t)2 * HBUF_HALVES * 2);
  int* flagsB = flagsA + 16 * 16;

  hipFuncSetAttribute(reinterpret_cast<const void*>(rnn_persistent),
                      hipFuncAttributeMaxDynamicSharedMemorySize, SMEM_BYTES);

  rnn_persistent<<<dim3(GB * GJ), dim3(256), SMEM_BYTES, stream>>>(
      x, Whx, Whh, bh, Wph, bp, out, hbuf, flagsA, flagsB);
}